// Round 6
// baseline (261.419 us; speedup 1.0000x reference)
//
#include <hip/hip_runtime.h>
#include <stdint.h>

#define B_ 8
#define N_ 2048
#define D_ 128
#define NT_ 32            // 64-wide k-tiles per batch
#define KT_ 8             // tiles per gemm block (ksplit = 4)
#define TILE_BYTES 16384  // ET tile image: 128 d x 64 k x 2B
#define PS_ ((size_t)B_ * N_ * D_)

typedef unsigned short u16;
typedef unsigned int u32;
using f32x4 = __attribute__((ext_vector_type(4))) float;
using bf16x8 = __attribute__((ext_vector_type(8))) short;
using u16x8 = __attribute__((ext_vector_type(8))) u16;

__device__ inline u16 f2bf(float x) {
  u32 u = __float_as_uint(x);
  return (u16)((u + 0x7FFFu + ((u >> 16) & 1u)) >> 16);
}
__device__ inline float bf2f(u16 h) { return __uint_as_float((u32)h << 16); }

__device__ inline void glds16(const void* g, void* l) {
  __builtin_amdgcn_global_load_lds((const __attribute__((address_space(1))) void*)g,
                                   (__attribute__((address_space(3))) void*)l, 16, 0, 0);
}

// ---------------------------------------------------------------------------
// Prep (257 blocks): 0..255 -> ET tile images; 256 -> W bf16 swizzled image.
// ---------------------------------------------------------------------------
__global__ __launch_bounds__(256) void prep_kernel(const float* __restrict__ E,
                                                   const float* __restrict__ W,
                                                   u16* __restrict__ ETsw,
                                                   u16* __restrict__ Wsw) {
  const int blk = blockIdx.x;
  const int t = threadIdx.x;
  if (blk == 256) {  // W[d][f] -> Wsw swizzled [d][k8^swz]
    const int d = t >> 1;
    const int swz = (d ^ (d >> 3)) & 7;
#pragma unroll
    for (int s = 0; s < 16; ++s) {
      const int k8 = (t & 1) * 16 + s;
      f32x4 v0 = *(const f32x4*)(W + d * 256 + k8 * 8);
      f32x4 v1 = *(const f32x4*)(W + d * 256 + k8 * 8 + 4);
      u16x8 pk;
#pragma unroll
      for (int e = 0; e < 4; ++e) { pk[e] = f2bf(v0[e]); pk[4 + e] = f2bf(v1[e]); }
      *(u16x8*)(Wsw + d * 256 + ((k8 ^ swz) << 3)) = pk;
    }
    return;
  }
  __shared__ float Els[64][132];
  const int b = blk >> 5;
  const int g = blk & 31;  // k-tile
  const float* Eb = E + ((size_t)b * N_ + g * 64) * D_;
#pragma unroll
  for (int s = 0; s < 8; ++s) {
    const int f4 = t + 256 * s;
    const int r = f4 >> 5;
    const int c4 = f4 & 31;
    f32x4 v = *(const f32x4*)(Eb + (size_t)r * D_ + c4 * 4);
#pragma unroll
    for (int e = 0; e < 4; ++e) Els[r][c4 * 4 + e] = v[e];
  }
  __syncthreads();
  u16* img = ETsw + ((size_t)b * NT_ + g) * (TILE_BYTES / 2);
  const int d = t >> 1;
  const int swz = (d ^ (d >> 3)) & 7;
#pragma unroll
  for (int gg = 0; gg < 4; ++gg) {
    const int grp = (t & 1) * 4 + gg;
    u16x8 pk;
#pragma unroll
    for (int e = 0; e < 8; ++e) pk[e] = f2bf(Els[grp * 8 + e][d]);
    *(u16x8*)(img + d * 64 + ((grp ^ swz) << 3)) = pk;
  }
}

// ---------------------------------------------------------------------------
// Main GEMM: Sp[ks][row][d] = sum_{k in quarter} C[b][k][j]*E[b][k][d].
// 1024 blocks = 8b x 32jt x 4ks (batch->XCD), 256 thr, 48KB LDS.
// Depth-2 reg prefetch of C (av ping-pong, fully static via STEP macro).
// vmcnt(4) steady (drains this tile's glds, keeps next av in flight);
// tail steps without LOAD_A must use vmcnt(0) (in-order vmcnt: glds newest).
// ---------------------------------------------------------------------------
__global__ __launch_bounds__(256) void gemm_kernel(const float* __restrict__ C,
                                                   const u16* __restrict__ ETsw,
                                                   u16* __restrict__ Sp,
                                                   int* __restrict__ zeros) {
  __shared__ __align__(16) u16 Asw[2][64 * 64];   // 16KB
  __shared__ __align__(16) u16 Bsw[2][128 * 64];  // 32KB
  const int phys = blockIdx.x;
  const int orig = (phys & 7) * 128 + (phys >> 3);  // 128 blocks per XCD = 1 batch
  const int b = orig >> 7;
  const int ks = (orig >> 5) & 3;
  const int jt = orig & 31;
  const int j0 = jt * 64;
  const int t = threadIdx.x;
  const int lane = t & 63;
  const int wave = t >> 6;
  const int wm = wave >> 1, wn = wave & 1;
  const int lm = lane & 15, lh = lane >> 4;
  const int aRow = t >> 4, aCol = t & 15;

  const float* Cb = C + (size_t)b * N_ * N_;
  const char* Eimg = (const char*)(ETsw + (size_t)b * NT_ * (TILE_BYTES / 2));
  int* zb = zeros + b * N_;
  const int g0 = ks * KT_;

  f32x4 acc[2][4];
#pragma unroll
  for (int i = 0; i < 2; ++i)
#pragma unroll
    for (int j = 0; j < 4; ++j) acc[i][j] = (f32x4)0.0f;
  f32x4 av[2][4];  // depth-2 ping-pong; ALL indices literal via macros

#define ISSUE_B(gi, buf)                                                          \
  {                                                                               \
    _Pragma("unroll") for (int s = 0; s < 4; ++s) {                               \
      const int chunk = s * 4 + wave;                                             \
      glds16(Eimg + (size_t)(gi)*TILE_BYTES + chunk * 1024 + lane * 16,           \
             (char*)&Bsw[buf][0] + chunk * 1024);                                 \
    }                                                                             \
  }
#define LOAD_A(gi, slot)                                                          \
  {                                                                               \
    _Pragma("unroll") for (int s = 0; s < 4; ++s) av[slot][s] =                   \
        *(const f32x4*)(Cb + (size_t)((gi)*64 + aRow + 16 * s) * N_ + j0 + aCol * 4); \
  }
#define WRITE_A(gi, buf, slot)                                                    \
  {                                                                               \
    _Pragma("unroll") for (int s = 0; s < 4; ++s) {                               \
      const int i = aRow + 16 * s;                                                \
      f32x4 v = av[slot][s];                                                      \
      int zc = (v[0] == 0.0f) + (v[1] == 0.0f) + (v[2] == 0.0f) + (v[3] == 0.0f);\
      if (__any(zc)) {  /* rare: exact-zero entries in C */                       \
        if (zc) atomicAdd(&zb[(gi)*64 + i], zc);                                  \
      }                                                                           \
      _Pragma("unroll") for (int e = 0; e < 4; ++e) {                             \
        const int jl = aCol * 4 + e;                                              \
        const int sz = (jl ^ (jl >> 3)) & 7;                                      \
        Asw[buf][jl * 64 + (i ^ (sz << 3))] = f2bf(v[e]);                         \
      }                                                                           \
    }                                                                             \
  }
#define MFMA_PHASE(buf)                                                           \
  {                                                                               \
    bf16x8 af[2][2], bfr[4][2];                                                   \
    _Pragma("unroll") for (int fm = 0; fm < 2; ++fm) {                            \
      const int jl = wm * 32 + fm * 16 + lm;                                      \
      const int sz = (jl ^ (jl >> 3)) & 7;                                        \
      _Pragma("unroll") for (int kf = 0; kf < 2; ++kf) {                          \
        const int K8 = kf * 32 + lh * 8;                                          \
        af[fm][kf] = *(const bf16x8*)&Asw[buf][jl * 64 + (K8 ^ (sz << 3))];       \
      }                                                                           \
    }                                                                             \
    _Pragma("unroll") for (int fn = 0; fn < 4; ++fn) {                            \
      const int nl = wn * 64 + fn * 16 + lm;                                      \
      const int sz = (nl ^ (nl >> 3)) & 7;                                        \
      _Pragma("unroll") for (int kf = 0; kf < 2; ++kf) {                          \
        const int K8 = kf * 32 + lh * 8;                                          \
        bfr[fn][kf] = *(const bf16x8*)&Bsw[buf][nl * 64 + (K8 ^ (sz << 3))];      \
      }                                                                           \
    }                                                                             \
    _Pragma("unroll") for (int kf = 0; kf < 2; ++kf)                              \
        _Pragma("unroll") for (int fm = 0; fm < 2; ++fm)                          \
        _Pragma("unroll") for (int fn = 0; fn < 4; ++fn) acc[fm][fn] =            \
        __builtin_amdgcn_mfma_f32_16x16x32_bf16(af[fm][kf], bfr[fn][kf],          \
                                                acc[fm][fn], 0, 0, 0);            \
  }
// One steady-state step; kt literal so (kt)&1 indices fold. DOLOAD/VMN literal.
#define STEP(kt, DOLOAD, VMSTR)                                                   \
  ISSUE_B(g0 + (kt) + 1, ((kt) + 1) & 1);                                         \
  __builtin_amdgcn_sched_barrier(0);                                              \
  MFMA_PHASE((kt) & 1);                                                           \
  __builtin_amdgcn_sched_barrier(0);                                              \
  WRITE_A(g0 + (kt) + 1, ((kt) + 1) & 1, (kt) & 1);                               \
  __builtin_amdgcn_sched_barrier(0);                                              \
  if (DOLOAD) LOAD_A(g0 + (kt) + 3, (kt) & 1);                                    \
  __builtin_amdgcn_sched_barrier(0);                                              \
  asm volatile("s_waitcnt " VMSTR ::: "memory");                                  \
  asm volatile("s_waitcnt lgkmcnt(0)" ::: "memory");                              \
  __builtin_amdgcn_sched_barrier(0);                                              \
  __builtin_amdgcn_s_barrier();                                                   \
  __builtin_amdgcn_sched_barrier(0);

  // ---- prologue: tile g0 staged; av0 <- g0+1, av1 <- g0+2 in flight
  ISSUE_B(g0, 0);
  LOAD_A(g0, 0);
  WRITE_A(g0, 0, 0);  // av consume drains glds(g0) too (prologue only)
  LOAD_A(g0 + 1, 0);
  LOAD_A(g0 + 2, 1);
  asm volatile("s_waitcnt lgkmcnt(0)" ::: "memory");
  __builtin_amdgcn_sched_barrier(0);
  __builtin_amdgcn_s_barrier();
  __builtin_amdgcn_sched_barrier(0);

  // ---- steady: tiles 0..6 compute, tile 7 staged by STEP(6)
  STEP(0, 1, "vmcnt(4)")
  STEP(1, 1, "vmcnt(4)")
  STEP(2, 1, "vmcnt(4)")
  STEP(3, 1, "vmcnt(4)")
  STEP(4, 1, "vmcnt(4)")
  STEP(5, 0, "vmcnt(0)")  // no LOAD_A: glds are newest, only vmcnt(0) drains them
  STEP(6, 0, "vmcnt(0)")
  MFMA_PHASE(1)  // tile 7 (staged into buf 1)

  u16* Sb = Sp + (size_t)ks * PS_ + ((size_t)b * N_ + j0) * D_;
#pragma unroll
  for (int fm = 0; fm < 2; ++fm)
#pragma unroll
    for (int fn = 0; fn < 4; ++fn)
#pragma unroll
      for (int r = 0; r < 4; ++r) {
        const int row = wm * 32 + fm * 16 + lh * 4 + r;
        const int col = wn * 64 + fn * 16 + lm;
        Sb[(size_t)row * D_ + col] = f2bf(acc[fm][fn][r]);
      }
#undef ISSUE_B
#undef LOAD_A
#undef WRITE_A
#undef MFMA_PHASE
#undef STEP
}

// ---------------------------------------------------------------------------
// Output GEMM: out[row][d] = relu(sum_f A[row][f]*W[d][f] + b[d]),
// A = [E | (Sp0+Sp1+Sp2+Sp3)/(2048-zeros)]. W via glds from pre-swizzled image.
// ---------------------------------------------------------------------------
__global__ __launch_bounds__(256) void out_kernel(const float* __restrict__ E,
                                                  const u16* __restrict__ Sp,
                                                  const int* __restrict__ zeros,
                                                  const u16* __restrict__ Wsw,
                                                  const float* __restrict__ bias,
                                                  float* __restrict__ out) {
  __shared__ __align__(16) u16 Wls[128 * 256];
  __shared__ __align__(16) u16 Als[32 * 256];
  const int r0 = blockIdx.x * 32;
  const int t = threadIdx.x;
  const int lane = t & 63;
  const int wave = t >> 6;
  const int lm = lane & 15, lh = lane >> 4;

#pragma unroll
  for (int s = 0; s < 16; ++s) {
    const int chunk = s * 4 + wave;
    glds16((const char*)Wsw + chunk * 1024 + lane * 16, (char*)Wls + chunk * 1024);
  }
  const int r = t >> 3, gq = t & 7;
  const int swzr = (r ^ (r >> 3)) & 7;
  const float idg = 1.0f / (2048.0f - (float)zeros[r0 + r]);
  const float* Er = E + (size_t)(r0 + r) * D_;
#pragma unroll
  for (int h = 0; h < 2; ++h) {
    const int k8 = gq + 8 * h;
    f32x4 v0 = *(const f32x4*)(Er + k8 * 8);
    f32x4 v1 = *(const f32x4*)(Er + k8 * 8 + 4);
    u16x8 pk;
#pragma unroll
    for (int e = 0; e < 4; ++e) { pk[e] = f2bf(v0[e]); pk[4 + e] = f2bf(v1[e]); }
    *(u16x8*)&Als[r * 256 + ((k8 ^ swzr) << 3)] = pk;
  }
  const size_t off = (size_t)(r0 + r) * D_;
#pragma unroll
  for (int h = 0; h < 2; ++h) {
    const int kq = gq + 8 * h;
    u16x8 p0 = *(const u16x8*)(Sp + 0 * PS_ + off + kq * 8);
    u16x8 p1 = *(const u16x8*)(Sp + 1 * PS_ + off + kq * 8);
    u16x8 p2 = *(const u16x8*)(Sp + 2 * PS_ + off + kq * 8);
    u16x8 p3 = *(const u16x8*)(Sp + 3 * PS_ + off + kq * 8);
    u16x8 pk;
#pragma unroll
    for (int e = 0; e < 8; ++e) {
      float sum = (bf2f(p0[e]) + bf2f(p1[e])) + (bf2f(p2[e]) + bf2f(p3[e]));
      pk[e] = f2bf(sum * idg);
    }
    *(u16x8*)&Als[r * 256 + (((16 + kq) ^ swzr) << 3)] = pk;
  }
  __syncthreads();  // drains glds (vmcnt) + ds writes (lgkm)

  f32x4 acc[2][2];
#pragma unroll
  for (int i = 0; i < 2; ++i)
#pragma unroll
    for (int j = 0; j < 2; ++j) acc[i][j] = (f32x4)0.0f;
  const int dbase = wave * 32;
#pragma unroll
  for (int kf = 0; kf < 8; ++kf) {
    bf16x8 af[2], bfr[2];
#pragma unroll
    for (int fm = 0; fm < 2; ++fm) {
      const int rr = fm * 16 + lm;
      const int sz = (rr ^ (rr >> 3)) & 7;
      af[fm] = *(const bf16x8*)&Als[rr * 256 + (((kf * 4 + lh) ^ sz) << 3)];
    }
#pragma unroll
    for (int fn = 0; fn < 2; ++fn) {
      const int d = dbase + fn * 16 + lm;
      const int sz = (d ^ (d >> 3)) & 7;
      bfr[fn] = *(const bf16x8*)&Wls[d * 256 + (((kf * 4 + lh) ^ sz) << 3)];
    }
#pragma unroll
    for (int fm = 0; fm < 2; ++fm)
#pragma unroll
      for (int fn = 0; fn < 2; ++fn)
        acc[fm][fn] = __builtin_amdgcn_mfma_f32_16x16x32_bf16(af[fm], bfr[fn],
                                                              acc[fm][fn], 0, 0, 0);
  }
  float bb[2] = {bias[dbase + lm], bias[dbase + 16 + lm]};
#pragma unroll
  for (int fm = 0; fm < 2; ++fm)
#pragma unroll
    for (int fn = 0; fn < 2; ++fn)
#pragma unroll
      for (int rr = 0; rr < 4; ++rr) {
        const int row = r0 + fm * 16 + lh * 4 + rr;
        const int d = dbase + fn * 16 + lm;
        float x = acc[fm][fn][rr] + bb[fn];
        out[(size_t)row * D_ + d] = x > 0.0f ? x : 0.0f;
      }
}

extern "C" void kernel_launch(void* const* d_in, const int* in_sizes, int n_in,
                              void* d_out, int out_size, void* d_ws, size_t ws_size,
                              hipStream_t stream) {
  (void)in_sizes; (void)n_in; (void)out_size; (void)ws_size;
  const float* E = (const float*)d_in[0];
  const float* C = (const float*)d_in[1];
  const float* W = (const float*)d_in[2];
  const float* bias = (const float*)d_in[3];
  float* out = (float*)d_out;

  // ws: zeros int[16K] | ETsw 4MB | Wsw 64KB | Sp bf16[4][B*N][D] (16.8MB)
  char* ws = (char*)d_ws;
  int* zeros = (int*)ws;
  u16* ETsw = (u16*)(ws + 65536);
  u16* Wsw = (u16*)(ws + 65536 + 4194304);
  u16* Sp = (u16*)(ws + 65536 + 4194304 + 65536);

  hipMemsetAsync(zeros, 0, B_ * N_ * sizeof(int), stream);
  hipLaunchKernelGGL(prep_kernel, dim3(257), dim3(256), 0, stream, E, W, ETsw, Wsw);
  // MEASUREMENT ROUND: gemm launched twice (idempotent Sp; zeros re-zeroed
  // between) so gemm gets its own top-5 counter row if >77us, and the
  // cold(gemm1)-vs-L3-warm(gemm2) delta separates memory cost from structure.
  hipLaunchKernelGGL(gemm_kernel, dim3(1024), dim3(256), 0, stream, C, ETsw, Sp, zeros);
  hipMemsetAsync(zeros, 0, B_ * N_ * sizeof(int), stream);
  hipLaunchKernelGGL(gemm_kernel, dim3(1024), dim3(256), 0, stream, C, ETsw, Sp, zeros);
  hipLaunchKernelGGL(out_kernel, dim3(512), dim3(256), 0, stream, E, Sp, zeros, Wsw, bias, out);
}

// Round 7
// 223.277 us; speedup vs baseline: 1.1708x; 1.1708x over previous
//
#include <hip/hip_runtime.h>
#include <stdint.h>

#define B_ 8
#define N_ 2048
#define D_ 128
#define NT_ 32            // 64-wide k-tiles per batch
#define KT_ 8             // tiles per gemm block (ksplit = 4)
#define TILE_BYTES 16384  // ET tile image: 128 d x 64 k x 2B
#define PS_ ((size_t)B_ * N_ * D_)

typedef unsigned short u16;
typedef unsigned int u32;
using f32x4 = __attribute__((ext_vector_type(4))) float;
using bf16x8 = __attribute__((ext_vector_type(8))) short;
using u16x8 = __attribute__((ext_vector_type(8))) u16;

__device__ inline u16 f2bf(float x) {
  u32 u = __float_as_uint(x);
  return (u16)((u + 0x7FFFu + ((u >> 16) & 1u)) >> 16);
}
__device__ inline float bf2f(u16 h) { return __uint_as_float((u32)h << 16); }

__device__ inline void glds16(const void* g, void* l) {
  __builtin_amdgcn_global_load_lds((const __attribute__((address_space(1))) void*)g,
                                   (__attribute__((address_space(3))) void*)l, 16, 0, 0);
}

// ---------------------------------------------------------------------------
// Prep (257 blocks): 0..255 -> ET tile images; 256 -> Wfrag image.
// Wfrag[idx]: 16B per (wave,fn,kf,lane) = MFMA B-fragment of bf16(W), so
// out_kernel loads W straight into VGPRs with coalesced 16B reads.
// ---------------------------------------------------------------------------
__global__ __launch_bounds__(256) void prep_kernel(const float* __restrict__ E,
                                                   const float* __restrict__ W,
                                                   u16* __restrict__ ETsw,
                                                   u16* __restrict__ Wfrag) {
  const int blk = blockIdx.x;
  const int t = threadIdx.x;
  if (blk == 256) {
#pragma unroll
    for (int i = 0; i < 16; ++i) {
      const int idx = i * 256 + t;
      const int lane = idx & 63;
      const int kf = (idx >> 6) & 7;
      const int fn = (idx >> 9) & 1;
      const int wv = idx >> 10;
      const int d = wv * 32 + fn * 16 + (lane & 15);
      const int kb = kf * 32 + (lane >> 4) * 8;
      u16x8 pk;
#pragma unroll
      for (int e = 0; e < 8; ++e) pk[e] = f2bf(W[d * 256 + kb + e]);
      *(u16x8*)(Wfrag + (size_t)idx * 8) = pk;
    }
    return;
  }
  __shared__ float Els[64][132];
  const int b = blk >> 5;
  const int g = blk & 31;  // k-tile
  const float* Eb = E + ((size_t)b * N_ + g * 64) * D_;
#pragma unroll
  for (int s = 0; s < 8; ++s) {
    const int f4 = t + 256 * s;
    const int r = f4 >> 5;
    const int c4 = f4 & 31;
    f32x4 v = *(const f32x4*)(Eb + (size_t)r * D_ + c4 * 4);
#pragma unroll
    for (int e = 0; e < 4; ++e) Els[r][c4 * 4 + e] = v[e];
  }
  __syncthreads();
  u16* img = ETsw + ((size_t)b * NT_ + g) * (TILE_BYTES / 2);
  const int d = t >> 1;
  const int swz = (d ^ (d >> 3)) & 7;
#pragma unroll
  for (int gg = 0; gg < 4; ++gg) {
    const int grp = (t & 1) * 4 + gg;
    u16x8 pk;
#pragma unroll
    for (int e = 0; e < 8; ++e) pk[e] = f2bf(Els[grp * 8 + e][d]);
    *(u16x8*)(img + d * 64 + ((grp ^ swz) << 3)) = pk;
  }
}

// ---------------------------------------------------------------------------
// Main GEMM: Sp[ks][row][d] = sum_{k in quarter} C[b][k][j]*E[b][k][d].
// 1024 blocks = 8b x 32jt x 4ks (batch->XCD), 256 thr, 48KB LDS.
// Depth-2 reg prefetch of C; vmcnt(4) steady, vmcnt(0) in tail steps.
// Measured (R6 double-launch delta): ~38-40 us per launch.
// ---------------------------------------------------------------------------
__global__ __launch_bounds__(256) void gemm_kernel(const float* __restrict__ C,
                                                   const u16* __restrict__ ETsw,
                                                   u16* __restrict__ Sp,
                                                   int* __restrict__ zeros) {
  __shared__ __align__(16) u16 Asw[2][64 * 64];   // 16KB
  __shared__ __align__(16) u16 Bsw[2][128 * 64];  // 32KB
  const int phys = blockIdx.x;
  const int orig = (phys & 7) * 128 + (phys >> 3);  // 128 blocks per XCD = 1 batch
  const int b = orig >> 7;
  const int ks = (orig >> 5) & 3;
  const int jt = orig & 31;
  const int j0 = jt * 64;
  const int t = threadIdx.x;
  const int lane = t & 63;
  const int wave = t >> 6;
  const int wm = wave >> 1, wn = wave & 1;
  const int lm = lane & 15, lh = lane >> 4;
  const int aRow = t >> 4, aCol = t & 15;

  const float* Cb = C + (size_t)b * N_ * N_;
  const char* Eimg = (const char*)(ETsw + (size_t)b * NT_ * (TILE_BYTES / 2));
  int* zb = zeros + b * N_;
  const int g0 = ks * KT_;

  f32x4 acc[2][4];
#pragma unroll
  for (int i = 0; i < 2; ++i)
#pragma unroll
    for (int j = 0; j < 4; ++j) acc[i][j] = (f32x4)0.0f;
  f32x4 av[2][4];  // depth-2 ping-pong; ALL indices literal via macros

#define ISSUE_B(gi, buf)                                                          \
  {                                                                               \
    _Pragma("unroll") for (int s = 0; s < 4; ++s) {                               \
      const int chunk = s * 4 + wave;                                             \
      glds16(Eimg + (size_t)(gi)*TILE_BYTES + chunk * 1024 + lane * 16,           \
             (char*)&Bsw[buf][0] + chunk * 1024);                                 \
    }                                                                             \
  }
#define LOAD_A(gi, slot)                                                          \
  {                                                                               \
    _Pragma("unroll") for (int s = 0; s < 4; ++s) av[slot][s] =                   \
        *(const f32x4*)(Cb + (size_t)((gi)*64 + aRow + 16 * s) * N_ + j0 + aCol * 4); \
  }
#define WRITE_A(gi, buf, slot)                                                    \
  {                                                                               \
    _Pragma("unroll") for (int s = 0; s < 4; ++s) {                               \
      const int i = aRow + 16 * s;                                                \
      f32x4 v = av[slot][s];                                                      \
      int zc = (v[0] == 0.0f) + (v[1] == 0.0f) + (v[2] == 0.0f) + (v[3] == 0.0f);\
      if (__any(zc)) {  /* rare: exact-zero entries in C */                       \
        if (zc) atomicAdd(&zb[(gi)*64 + i], zc);                                  \
      }                                                                           \
      _Pragma("unroll") for (int e = 0; e < 4; ++e) {                             \
        const int jl = aCol * 4 + e;                                              \
        const int sz = (jl ^ (jl >> 3)) & 7;                                      \
        Asw[buf][jl * 64 + (i ^ (sz << 3))] = f2bf(v[e]);                         \
      }                                                                           \
    }                                                                             \
  }
#define MFMA_PHASE(buf)                                                           \
  {                                                                               \
    bf16x8 af[2][2], bfr[4][2];                                                   \
    _Pragma("unroll") for (int fm = 0; fm < 2; ++fm) {                            \
      const int jl = wm * 32 + fm * 16 + lm;                                      \
      const int sz = (jl ^ (jl >> 3)) & 7;                                        \
      _Pragma("unroll") for (int kf = 0; kf < 2; ++kf) {                          \
        const int K8 = kf * 32 + lh * 8;                                          \
        af[fm][kf] = *(const bf16x8*)&Asw[buf][jl * 64 + (K8 ^ (sz << 3))];       \
      }                                                                           \
    }                                                                             \
    _Pragma("unroll") for (int fn = 0; fn < 4; ++fn) {                            \
      const int nl = wn * 64 + fn * 16 + lm;                                      \
      const int sz = (nl ^ (nl >> 3)) & 7;                                        \
      _Pragma("unroll") for (int kf = 0; kf < 2; ++kf) {                          \
        const int K8 = kf * 32 + lh * 8;                                          \
        bfr[fn][kf] = *(const bf16x8*)&Bsw[buf][nl * 64 + (K8 ^ (sz << 3))];      \
      }                                                                           \
    }                                                                             \
    _Pragma("unroll") for (int kf = 0; kf < 2; ++kf)                              \
        _Pragma("unroll") for (int fm = 0; fm < 2; ++fm)                          \
        _Pragma("unroll") for (int fn = 0; fn < 4; ++fn) acc[fm][fn] =            \
        __builtin_amdgcn_mfma_f32_16x16x32_bf16(af[fm][kf], bfr[fn][kf],          \
                                                acc[fm][fn], 0, 0, 0);            \
  }
#define STEP(kt, DOLOAD, VMSTR)                                                   \
  ISSUE_B(g0 + (kt) + 1, ((kt) + 1) & 1);                                         \
  __builtin_amdgcn_sched_barrier(0);                                              \
  MFMA_PHASE((kt) & 1);                                                           \
  __builtin_amdgcn_sched_barrier(0);                                              \
  WRITE_A(g0 + (kt) + 1, ((kt) + 1) & 1, (kt) & 1);                               \
  __builtin_amdgcn_sched_barrier(0);                                              \
  if (DOLOAD) LOAD_A(g0 + (kt) + 3, (kt) & 1);                                    \
  __builtin_amdgcn_sched_barrier(0);                                              \
  asm volatile("s_waitcnt " VMSTR ::: "memory");                                  \
  asm volatile("s_waitcnt lgkmcnt(0)" ::: "memory");                              \
  __builtin_amdgcn_sched_barrier(0);                                              \
  __builtin_amdgcn_s_barrier();                                                   \
  __builtin_amdgcn_sched_barrier(0);

  // ---- prologue: tile g0 staged; av0 <- g0+1, av1 <- g0+2 in flight
  ISSUE_B(g0, 0);
  LOAD_A(g0, 0);
  WRITE_A(g0, 0, 0);  // av consume drains glds(g0) too (prologue only)
  LOAD_A(g0 + 1, 0);
  LOAD_A(g0 + 2, 1);
  asm volatile("s_waitcnt lgkmcnt(0)" ::: "memory");
  __builtin_amdgcn_sched_barrier(0);
  __builtin_amdgcn_s_barrier();
  __builtin_amdgcn_sched_barrier(0);

  STEP(0, 1, "vmcnt(4)")
  STEP(1, 1, "vmcnt(4)")
  STEP(2, 1, "vmcnt(4)")
  STEP(3, 1, "vmcnt(4)")
  STEP(4, 1, "vmcnt(4)")
  STEP(5, 0, "vmcnt(0)")  // no LOAD_A: glds are newest, only vmcnt(0) drains them
  STEP(6, 0, "vmcnt(0)")
  MFMA_PHASE(1)  // tile 7 (staged into buf 1)

  u16* Sb = Sp + (size_t)ks * PS_ + ((size_t)b * N_ + j0) * D_;
#pragma unroll
  for (int fm = 0; fm < 2; ++fm)
#pragma unroll
    for (int fn = 0; fn < 4; ++fn)
#pragma unroll
      for (int r = 0; r < 4; ++r) {
        const int row = wm * 32 + fm * 16 + lh * 4 + r;
        const int col = wn * 64 + fn * 16 + lm;
        Sb[(size_t)row * D_ + col] = f2bf(acc[fm][fn][r]);
      }
#undef ISSUE_B
#undef LOAD_A
#undef WRITE_A
#undef MFMA_PHASE
#undef STEP
}

// ---------------------------------------------------------------------------
// Output GEMM: out[row][d] = relu(sum_f A[row][f]*W[d][f] + b[d]),
// A = [E | (Sp0..Sp3)/(2048-zeros)]. W lives in VGPRs (frag image, no LDS):
// LDS = 16KB Als only -> occupancy VGPR-bound (~3-4 blocks/CU vs 2 before).
// 512 blocks x 256 thr.
// ---------------------------------------------------------------------------
__global__ __launch_bounds__(256) void out_kernel(const float* __restrict__ E,
                                                  const u16* __restrict__ Sp,
                                                  const int* __restrict__ zeros,
                                                  const u16* __restrict__ Wfrag,
                                                  const float* __restrict__ bias,
                                                  float* __restrict__ out) {
  __shared__ __align__(16) u16 Als[32 * 256];  // 16KB
  const int r0 = blockIdx.x * 32;
  const int t = threadIdx.x;
  const int lane = t & 63;
  const int wave = t >> 6;
  const int lm = lane & 15, lh = lane >> 4;

  // ---- W fragments -> VGPR. Same 16B per corresponding lane in every block:
  // pure L2 broadcast. 16 coalesced global_load_dwordx4 per thread.
  bf16x8 wf[2][8];
#pragma unroll
  for (int fn = 0; fn < 2; ++fn)
#pragma unroll
    for (int kf = 0; kf < 8; ++kf)
      wf[fn][kf] = *(const bf16x8*)(Wfrag +
          (((size_t)(wave * 2 + fn) * 8 + kf) * 64 + lane) * 8);

  // ---- stage A rows: E half k8=0..15, (sum Sp)/deg half k8=16..31
  const int r = t >> 3, gq = t & 7;
  const int swzr = (r ^ (r >> 3)) & 7;
  const float idg = 1.0f / (2048.0f - (float)zeros[r0 + r]);
  const float* Er = E + (size_t)(r0 + r) * D_;
#pragma unroll
  for (int h = 0; h < 2; ++h) {
    const int k8 = gq + 8 * h;
    f32x4 v0 = *(const f32x4*)(Er + k8 * 8);
    f32x4 v1 = *(const f32x4*)(Er + k8 * 8 + 4);
    u16x8 pk;
#pragma unroll
    for (int e = 0; e < 4; ++e) { pk[e] = f2bf(v0[e]); pk[4 + e] = f2bf(v1[e]); }
    *(u16x8*)&Als[r * 256 + ((k8 ^ swzr) << 3)] = pk;
  }
  const size_t off = (size_t)(r0 + r) * D_;
#pragma unroll
  for (int h = 0; h < 2; ++h) {
    const int kq = gq + 8 * h;
    u16x8 p0 = *(const u16x8*)(Sp + 0 * PS_ + off + kq * 8);
    u16x8 p1 = *(const u16x8*)(Sp + 1 * PS_ + off + kq * 8);
    u16x8 p2 = *(const u16x8*)(Sp + 2 * PS_ + off + kq * 8);
    u16x8 p3 = *(const u16x8*)(Sp + 3 * PS_ + off + kq * 8);
    u16x8 pk;
#pragma unroll
    for (int e = 0; e < 8; ++e) {
      float sum = (bf2f(p0[e]) + bf2f(p1[e])) + (bf2f(p2[e]) + bf2f(p3[e]));
      pk[e] = f2bf(sum * idg);
    }
    *(u16x8*)&Als[r * 256 + (((16 + kq) ^ swzr) << 3)] = pk;
  }
  __syncthreads();

  f32x4 acc[2][2];
#pragma unroll
  for (int i = 0; i < 2; ++i)
#pragma unroll
    for (int j = 0; j < 2; ++j) acc[i][j] = (f32x4)0.0f;
  const int dbase = wave * 32;
#pragma unroll
  for (int kf = 0; kf < 8; ++kf) {
    bf16x8 af[2];
#pragma unroll
    for (int fm = 0; fm < 2; ++fm) {
      const int rr = fm * 16 + lm;
      const int sz = (rr ^ (rr >> 3)) & 7;
      af[fm] = *(const bf16x8*)&Als[rr * 256 + (((kf * 4 + lh) ^ sz) << 3)];
    }
#pragma unroll
    for (int fm = 0; fm < 2; ++fm)
#pragma unroll
      for (int fn = 0; fn < 2; ++fn)
        acc[fm][fn] = __builtin_amdgcn_mfma_f32_16x16x32_bf16(af[fm], wf[fn][kf],
                                                              acc[fm][fn], 0, 0, 0);
  }
  float bb[2] = {bias[dbase + lm], bias[dbase + 16 + lm]};
#pragma unroll
  for (int fm = 0; fm < 2; ++fm)
#pragma unroll
    for (int fn = 0; fn < 2; ++fn)
#pragma unroll
      for (int rr = 0; rr < 4; ++rr) {
        const int row = r0 + fm * 16 + lh * 4 + rr;
        const int d = dbase + fn * 16 + lm;
        float x = acc[fm][fn][rr] + bb[fn];
        out[(size_t)row * D_ + d] = x > 0.0f ? x : 0.0f;
      }
}

extern "C" void kernel_launch(void* const* d_in, const int* in_sizes, int n_in,
                              void* d_out, int out_size, void* d_ws, size_t ws_size,
                              hipStream_t stream) {
  (void)in_sizes; (void)n_in; (void)out_size; (void)ws_size;
  const float* E = (const float*)d_in[0];
  const float* C = (const float*)d_in[1];
  const float* W = (const float*)d_in[2];
  const float* bias = (const float*)d_in[3];
  float* out = (float*)d_out;

  // ws: zeros int[16K] | ETsw 4MB | Wfrag 64KB | Sp bf16[4][B*N][D] (16.8MB)
  char* ws = (char*)d_ws;
  int* zeros = (int*)ws;
  u16* ETsw = (u16*)(ws + 65536);
  u16* Wfrag = (u16*)(ws + 65536 + 4194304);
  u16* Sp = (u16*)(ws + 65536 + 4194304 + 65536);

  hipMemsetAsync(zeros, 0, B_ * N_ * sizeof(int), stream);
  hipLaunchKernelGGL(prep_kernel, dim3(257), dim3(256), 0, stream, E, W, ETsw, Wfrag);
  hipLaunchKernelGGL(gemm_kernel, dim3(1024), dim3(256), 0, stream, C, ETsw, Sp, zeros);
  hipLaunchKernelGGL(out_kernel, dim3(512), dim3(256), 0, stream, E, Sp, zeros, Wfrag, bias, out);
}